// Round 21
// baseline (2294.827 us; speedup 1.0000x reference)
//
#include <hip/hip_runtime.h>
#include <math.h>

// ROUND 21: qk_gemm_f64 bank-conflict fix — strided microtile (m=ty+16i,
// n=tx+16j). B-reads Bs[kk][tx+16j] hit 16 distinct even banks (conflict-
// free, was 4-way on Bs[kk][4tx+j] = measured 2.01e8 extra cycles). Per-
// element FMA order unchanged -> bit-identical output. Other kernels frozen.

// ---------------- K1: q,k GEMM fp64, 64x64 tile, strided 4x4/thread ----------------
__global__ __launch_bounds__(256) void qk_gemm_f64(
    const float* __restrict__ X, const float* __restrict__ W,
    const float* __restrict__ bias,
    double* __restrict__ qT, double* __restrict__ kT, int b0)
{
  __shared__ double As[16][68];   // [kk][m]
  __shared__ double Bs[16][68];   // [kk][n]
  const int t = threadIdx.x, tx = t & 15, ty = t >> 4;
  const int n0 = blockIdx.x * 64;      // 0..2047 (q,k cols)
  const int m0 = blockIdx.y * 64;      // chunk-local row
  double acc[4][4] = {};
  const size_t xrow0 = (size_t)b0 * 1024 + m0;

  for (int k0 = 0; k0 < 1024; k0 += 16) {
    __syncthreads();
    {
      int r = t >> 2, kq = (t & 3) << 2;
      float4 xv = *(const float4*)&X[(xrow0 + r) * 1024 + k0 + kq];
      As[kq + 0][r] = (double)xv.x;
      As[kq + 1][r] = (double)xv.y;
      As[kq + 2][r] = (double)xv.z;
      As[kq + 3][r] = (double)xv.w;
      int kr = t >> 4, cq = (t & 15) << 2;
      float4 wv = *(const float4*)&W[(size_t)(k0 + kr) * 3072 + n0 + cq];
      Bs[kr][cq + 0] = (double)wv.x;
      Bs[kr][cq + 1] = (double)wv.y;
      Bs[kr][cq + 2] = (double)wv.z;
      Bs[kr][cq + 3] = (double)wv.w;
    }
    __syncthreads();
#pragma unroll
    for (int kk = 0; kk < 16; ++kk) {
      double a0 = As[kk][ty +  0], a1 = As[kk][ty + 16];
      double a2 = As[kk][ty + 32], a3 = As[kk][ty + 48];
      double c0 = Bs[kk][tx +  0], c1 = Bs[kk][tx + 16];
      double c2 = Bs[kk][tx + 32], c3 = Bs[kk][tx + 48];
      acc[0][0] = fma(a0, c0, acc[0][0]); acc[0][1] = fma(a0, c1, acc[0][1]);
      acc[0][2] = fma(a0, c2, acc[0][2]); acc[0][3] = fma(a0, c3, acc[0][3]);
      acc[1][0] = fma(a1, c0, acc[1][0]); acc[1][1] = fma(a1, c1, acc[1][1]);
      acc[1][2] = fma(a1, c2, acc[1][2]); acc[1][3] = fma(a1, c3, acc[1][3]);
      acc[2][0] = fma(a2, c0, acc[2][0]); acc[2][1] = fma(a2, c1, acc[2][1]);
      acc[2][2] = fma(a2, c2, acc[2][2]); acc[2][3] = fma(a2, c3, acc[2][3]);
      acc[3][0] = fma(a3, c0, acc[3][0]); acc[3][1] = fma(a3, c1, acc[3][1]);
      acc[3][2] = fma(a3, c2, acc[3][2]); acc[3][3] = fma(a3, c3, acc[3][3]);
    }
  }
  double* T = (n0 < 1024) ? qT : kT;
  const int nn = n0 & 1023;
  const int h = nn >> 6;              // 64-wide tile = one head
  const int bl = m0 >> 10;
  const int sb = m0 & 1023;
  const size_t hb = (size_t)(bl * 16 + h) * 64;
#pragma unroll
  for (int j = 0; j < 4; ++j) {
    const int d = tx + 16 * j;
    double bz = (double)bias[n0 + d];
    size_t sidx = ((hb + d) << 10) + sb + ty;
#pragma unroll
    for (int i = 0; i < 4; ++i)
      T[sidx + 16 * i] = acc[i][j] + bz;
  }
}

// ---------------- K2: v GEMM fp32, 128x128 tile ----------------
__global__ __launch_bounds__(256) void v_gemm_f32(
    const float* __restrict__ X, const float* __restrict__ W,
    const float* __restrict__ bias, float* __restrict__ Vp, int b0)
{
  __shared__ __align__(16) float As[16][132];
  __shared__ __align__(16) float Bs[16][132];
  const int t = threadIdx.x, tx = t & 15, ty = t >> 4;
  const int n0 = blockIdx.x * 128;     // 0..1023 (v cols)
  const int m0 = blockIdx.y * 128;     // chunk-local row
  float acc[2][2][4][4] = {};
  const size_t xrow0 = (size_t)b0 * 1024 + m0;

  for (int k0 = 0; k0 < 1024; k0 += 16) {
    __syncthreads();
#pragma unroll
    for (int p = 0; p < 2; ++p) {
      int f = p * 256 + t;
      int r = f >> 2, kq = (f & 3) << 2;
      float4 xv = *(const float4*)&X[(xrow0 + r) * 1024 + k0 + kq];
      As[kq + 0][r] = xv.x; As[kq + 1][r] = xv.y;
      As[kq + 2][r] = xv.z; As[kq + 3][r] = xv.w;
      int kr = f >> 5, cq = (f & 31) << 2;
      *(float4*)&Bs[kr][cq] = *(const float4*)&W[(size_t)(k0 + kr) * 3072 + 2048 + n0 + cq];
    }
    __syncthreads();
#pragma unroll
    for (int kk = 0; kk < 16; ++kk) {
      float4 A0 = *(const float4*)&As[kk][4 * ty];
      float4 A1 = *(const float4*)&As[kk][64 + 4 * ty];
      float4 B0 = *(const float4*)&Bs[kk][4 * tx];
      float4 B1 = *(const float4*)&Bs[kk][64 + 4 * tx];
      float a[2][4] = {{A0.x, A0.y, A0.z, A0.w}, {A1.x, A1.y, A1.z, A1.w}};
      float b[2][4] = {{B0.x, B0.y, B0.z, B0.w}, {B1.x, B1.y, B1.z, B1.w}};
#pragma unroll
      for (int ri = 0; ri < 2; ++ri)
#pragma unroll
        for (int i = 0; i < 4; ++i)
#pragma unroll
          for (int ci = 0; ci < 2; ++ci)
#pragma unroll
            for (int j = 0; j < 4; ++j)
              acc[ri][ci][i][j] = fmaf(a[ri][i], b[ci][j], acc[ri][ci][i][j]);
    }
  }
  const int bl = m0 >> 10;
  const int sb = m0 & 1023;
#pragma unroll
  for (int ci = 0; ci < 2; ++ci) {
    int h = (n0 >> 6) + ci;
    float bz[4];
#pragma unroll
    for (int j = 0; j < 4; ++j) bz[j] = bias[2048 + n0 + 64 * ci + 4 * tx + j];
#pragma unroll
    for (int ri = 0; ri < 2; ++ri)
#pragma unroll
      for (int i = 0; i < 4; ++i) {
        int s = sb + 64 * ri + 4 * ty + i;
        float4 vv = make_float4(acc[ri][ci][i][0] + bz[0], acc[ri][ci][i][1] + bz[1],
                                acc[ri][ci][i][2] + bz[2], acc[ri][ci][i][3] + bz[3]);
        *(float4*)&Vp[((size_t)(bl * 16 + h) * 1024 + s) * 64 + 4 * tx] = vv;
      }
  }
}

// ---------------- K3: fused attention v2 (r20, unchanged) ----------------
__global__ __launch_bounds__(256) void attn_fused(
    const double* __restrict__ qT, const double* __restrict__ kT,
    const float* __restrict__ Vp, const float* __restrict__ Mask,
    float* __restrict__ AO, int b0)
{
  __shared__ double Qs[64][64];
  __shared__ double KVd[64][64];
  const int t = threadIdx.x, tx = t & 15, ty = t >> 4;
  const int bh = blockIdx.y;
  const int bl = bh >> 4, h = bh & 15;
  const int bg = b0 + bl;
  const int q0 = blockIdx.x * 64;
  const double* qTb = qT + (size_t)bh * 65536;
  const double* kTb = kT + (size_t)bh * 65536;
  const float*  Vb  = Vp + (size_t)bh * 65536;
  const float*  mb  = Mask + (size_t)bg * 1048576 + (size_t)q0 * 1024;
  float* Ps = (float*)&KVd[0][0];
  float* Vf = (float*)((char*)&KVd[0][0] + 16384);

#pragma unroll
  for (int p = 0; p < 8; ++p) {
    int f = p * 256 + t;
    int d = f >> 5, c = f & 31;
    *(double2*)&Qs[d][2 * c] = *(const double2*)&qTb[(size_t)d * 1024 + q0 + 2 * c];
  }

  double Mreg[4] = {-1e300, -1e300, -1e300, -1e300};
  float Lreg[4] = {0.f, 0.f, 0.f, 0.f};
  float o[4][4] = {};

  for (int kt = 0; kt < 16; ++kt) {
    const int k0 = kt * 64;
    __syncthreads();
#pragma unroll
    for (int p = 0; p < 8; ++p) {
      int f = p * 256 + t;
      int d = f >> 5, c = f & 31;
      *(double2*)&KVd[d][2 * c] = *(const double2*)&kTb[(size_t)d * 1024 + k0 + 2 * c];
    }
    __syncthreads();
    double s[4][4] = {};
#pragma unroll 4
    for (int d = 0; d < 64; ++d) {
      double2 qa = *(const double2*)&Qs[d][2 * ty];
      double2 qb = *(const double2*)&Qs[d][2 * ty + 32];
      double2 ka = *(const double2*)&KVd[d][2 * tx];
      double2 kb = *(const double2*)&KVd[d][2 * tx + 32];
      double aq[4] = {qa.x, qa.y, qb.x, qb.y};
      double ak[4] = {ka.x, ka.y, kb.x, kb.y};
#pragma unroll
      for (int i = 0; i < 4; ++i)
#pragma unroll
        for (int j = 0; j < 4; ++j)
          s[i][j] = fma(aq[i], ak[j], s[i][j]);
    }
    __syncthreads();
    float al[4];
#pragma unroll
    for (int i = 0; i < 4; ++i) {
      const int qi = 2 * ty + (i & 1) + (i >> 1) * 32;
      float2 m01 = *(const float2*)&mb[(size_t)qi * 1024 + k0 + 2 * tx];
      float2 m23 = *(const float2*)&mb[(size_t)qi * 1024 + k0 + 2 * tx + 32];
      double z0 = (m01.x != 0.f) ? s[i][0] * -1.25e8 : 0.0;
      double z1 = (m01.y != 0.f) ? s[i][1] * -1.25e8 : 0.0;
      double z2 = (m23.x != 0.f) ? s[i][2] * -1.25e8 : 0.0;
      double z3 = (m23.y != 0.f) ? s[i][3] * -1.25e8 : 0.0;
      double mx = fmax(fmax(z0, z1), fmax(z2, z3));
#pragma unroll
      for (int w = 1; w < 16; w <<= 1) mx = fmax(mx, __shfl_xor(mx, w));
      double nM = fmax(Mreg[i], mx);
      double da = Mreg[i] - nM;
      al[i] = (da < -80.0) ? 0.f : expf((float)da);
      double d0 = z0 - nM, d1 = z1 - nM, d2 = z2 - nM, d3 = z3 - nM;
      float p0 = (d0 < -80.0) ? 0.f : expf((float)d0);
      float p1 = (d1 < -80.0) ? 0.f : expf((float)d1);
      float p2 = (d2 < -80.0) ? 0.f : expf((float)d2);
      float p3 = (d3 < -80.0) ? 0.f : expf((float)d3);
      float ps = ((p0 + p1) + p2) + p3;
#pragma unroll
      for (int w = 1; w < 16; w <<= 1) ps += __shfl_xor(ps, w);
      Lreg[i] = Lreg[i] * al[i] + ps;
      Mreg[i] = nM;
      *(float2*)&Ps[qi * 64 + 2 * tx] = make_float2(p0, p1);
      *(float2*)&Ps[qi * 64 + 2 * tx + 32] = make_float2(p2, p3);
    }
#pragma unroll
    for (int p = 0; p < 4; ++p) {
      int f = p * 256 + t;
      *(float4*)&Vf[4 * f] = *(const float4*)&Vb[(size_t)k0 * 64 + 4 * f];
    }
    __syncthreads();
#pragma unroll
    for (int i = 0; i < 4; ++i) {
      o[i][0] *= al[i]; o[i][1] *= al[i]; o[i][2] *= al[i]; o[i][3] *= al[i];
    }
#pragma unroll 4
    for (int kk = 0; kk < 64; kk += 4) {
      float4 vv0 = *(const float4*)&Vf[(kk + 0) * 64 + 4 * tx];
      float4 vv1 = *(const float4*)&Vf[(kk + 1) * 64 + 4 * tx];
      float4 vv2 = *(const float4*)&Vf[(kk + 2) * 64 + 4 * tx];
      float4 vv3 = *(const float4*)&Vf[(kk + 3) * 64 + 4 * tx];
#pragma unroll
      for (int i = 0; i < 4; ++i) {
        const int qi = 2 * ty + (i & 1) + (i >> 1) * 32;
        float4 pa = *(const float4*)&Ps[qi * 64 + kk];
        o[i][0] = fmaf(pa.x, vv0.x, o[i][0]);
        o[i][0] = fmaf(pa.y, vv1.x, o[i][0]);
        o[i][0] = fmaf(pa.z, vv2.x, o[i][0]);
        o[i][0] = fmaf(pa.w, vv3.x, o[i][0]);
        o[i][1] = fmaf(pa.x, vv0.y, o[i][1]);
        o[i][1] = fmaf(pa.y, vv1.y, o[i][1]);
        o[i][1] = fmaf(pa.z, vv2.y, o[i][1]);
        o[i][1] = fmaf(pa.w, vv3.y, o[i][1]);
        o[i][2] = fmaf(pa.x, vv0.z, o[i][2]);
        o[i][2] = fmaf(pa.y, vv1.z, o[i][2]);
        o[i][2] = fmaf(pa.z, vv2.z, o[i][2]);
        o[i][2] = fmaf(pa.w, vv3.z, o[i][2]);
        o[i][3] = fmaf(pa.x, vv0.w, o[i][3]);
        o[i][3] = fmaf(pa.y, vv1.w, o[i][3]);
        o[i][3] = fmaf(pa.z, vv2.w, o[i][3]);
        o[i][3] = fmaf(pa.w, vv3.w, o[i][3]);
      }
    }
  }
#pragma unroll
  for (int i = 0; i < 4; ++i) {
    const int qi = 2 * ty + (i & 1) + (i >> 1) * 32;
    float inv = (Lreg[i] > 0.f) ? 1.f / Lreg[i] : 0.f;
    float4 vv = make_float4(o[i][0] * inv, o[i][1] * inv, o[i][2] * inv, o[i][3] * inv);
    *(float4*)&AO[(size_t)(bl * 1024 + q0 + qi) * 1024 + h * 64 + 4 * tx] = vv;
  }
}

// ---------------- K4: output projection fp32, 128x128 tile -> FP32 out ----------------
__global__ __launch_bounds__(256) void proj_gemm(
    const float* __restrict__ AO, const float* __restrict__ W,
    const float* __restrict__ bias, float* __restrict__ Out, int b0)
{
  __shared__ __align__(16) float As[16][132];
  __shared__ __align__(16) float Bs[16][132];
  const int t = threadIdx.x, tx = t & 15, ty = t >> 4;
  const int n0 = blockIdx.x * 128;
  const int m0l = blockIdx.y * 128;
  float acc[2][2][4][4] = {};

  for (int k0 = 0; k0 < 1024; k0 += 16) {
    __syncthreads();
#pragma unroll
    for (int p = 0; p < 2; ++p) {
      int f = p * 256 + t;
      int r = f >> 2, kq = (f & 3) << 2;
      float4 av = *(const float4*)&AO[(size_t)(m0l + r) * 1024 + k0 + kq];
      As[kq + 0][r] = av.x; As[kq + 1][r] = av.y;
      As[kq + 2][r] = av.z; As[kq + 3][r] = av.w;
      int kr = f >> 5, cq = (f & 31) << 2;
      *(float4*)&Bs[kr][cq] = *(const float4*)&W[(size_t)(k0 + kr) * 1024 + n0 + cq];
    }
    __syncthreads();
#pragma unroll
    for (int kk = 0; kk < 16; ++kk) {
      float4 A0 = *(const float4*)&As[kk][4 * ty];
      float4 A1 = *(const float4*)&As[kk][64 + 4 * ty];
      float4 B0 = *(const float4*)&Bs[kk][4 * tx];
      float4 B1 = *(const float4*)&Bs[kk][64 + 4 * tx];
      float a[2][4] = {{A0.x, A0.y, A0.z, A0.w}, {A1.x, A1.y, A1.z, A1.w}};
      float b[2][4] = {{B0.x, B0.y, B0.z, B0.w}, {B1.x, B1.y, B1.z, B1.w}};
#pragma unroll
      for (int ri = 0; ri < 2; ++ri)
#pragma unroll
        for (int i = 0; i < 4; ++i)
#pragma unroll
          for (int ci = 0; ci < 2; ++ci)
#pragma unroll
            for (int j = 0; j < 4; ++j)
              acc[ri][ci][i][j] = fmaf(a[ri][i], b[ci][j], acc[ri][ci][i][j]);
    }
  }
#pragma unroll
  for (int ci = 0; ci < 2; ++ci) {
    float bz[4];
#pragma unroll
    for (int j = 0; j < 4; ++j) bz[j] = bias[n0 + 64 * ci + 4 * tx + j];
#pragma unroll
    for (int ri = 0; ri < 2; ++ri)
#pragma unroll
      for (int i = 0; i < 4; ++i) {
        float4 vv = make_float4(acc[ri][ci][i][0] + bz[0], acc[ri][ci][i][1] + bz[1],
                                acc[ri][ci][i][2] + bz[2], acc[ri][ci][i][3] + bz[3]);
        size_t row = (size_t)b0 * 1024 + m0l + 64 * ri + 4 * ty + i;
        *(float4*)&Out[row * 1024 + n0 + 64 * ci + 4 * tx] = vv;
      }
  }
}

extern "C" void kernel_launch(void* const* d_in, const int* in_sizes, int n_in,
                              void* d_out, int out_size, void* d_ws, size_t ws_size,
                              hipStream_t stream) {
  (void)in_sizes; (void)n_in; (void)out_size;
  const float* x      = (const float*)d_in[0];
  const float* mask   = (const float*)d_in[1];
  const float* W_attn = (const float*)d_in[2];
  const float* b_attn = (const float*)d_in[3];
  const float* W_proj = (const float*)d_in[4];
  const float* b_proj = (const float*)d_in[5];
  float* out = (float*)d_out;

  int CB = (ws_size >= (192ull << 20)) ? 8
         : (ws_size >= (96ull  << 20)) ? 4
         : (ws_size >= (48ull  << 20)) ? 2 : 1;

  char* base = (char*)d_ws;
  double* qT = (double*)base;
  double* kT = (double*)(base + (size_t)CB * (8ull  << 20));
  float*  Vp = (float*)(base + (size_t)CB * (16ull << 20));
  float*  AO = (float*)(base + (size_t)CB * (20ull << 20));

  for (int b0 = 0; b0 < 8; b0 += CB) {
    qk_gemm_f64<<<dim3(32, 16 * CB), 256, 0, stream>>>(x, W_attn, b_attn, qT, kT, b0);
    v_gemm_f32<<<dim3(8, 8 * CB), 256, 0, stream>>>(x, W_attn, b_attn, Vp, b0);
    attn_fused<<<dim3(16, 16 * CB), 256, 0, stream>>>(qT, kT, Vp, mask, AO, b0);
    proj_gemm<<<dim3(8, 8 * CB), 256, 0, stream>>>(AO, W_proj, b_proj, out, b0);
  }
}

// Round 23
// 2159.742 us; speedup vs baseline: 1.0625x; 1.0625x over previous
//
#include <hip/hip_runtime.h>
#include <math.h>

// ROUND 23: self-calibrating f64-MFMA qk_gemm. r22's fixed-layout guess
// produced a wrong field (7.578); instead of guessing again, the kernel
// measures the real D-fragment layout at runtime (5 scalar fp64 refs
// accumulated alongside; wave0 compares and broadcasts a mode):
//   mode 1: D[4*l4+r][lm]   mode 2: D[l4+4*r][lm]
//   mode 3: D[lm][4*l4+r]   mode 4: D[lm][l4+4*r]
//   mode 0: A/B model wrong -> full VALU fallback (guaranteed correct).
// attn/v_gemm/proj unchanged (r20 forms).

typedef double f64x4 __attribute__((ext_vector_type(4)));

// ---------------- K1: q,k GEMM fp64 MFMA + runtime layout calibration ----------------
__global__ __launch_bounds__(256) void qk_gemm_f64(
    const float* __restrict__ X, const float* __restrict__ W,
    const float* __restrict__ bias,
    double* __restrict__ qT, double* __restrict__ kT, int b0)
{
  __shared__ double As[16][66];   // [k][m]
  __shared__ double Bs[16][66];   // [k][n]
  __shared__ int s_mode;
  const int t = threadIdx.x;
  const int lane = t & 63, w = t >> 6;        // 4 waves
  const int lm = lane & 15, l4 = lane >> 4;
  const int m0w = (w & 1) * 32, n0w = (w >> 1) * 32;
  const int n0 = blockIdx.x * 64;      // 0..2047
  const int m0 = blockIdx.y * 64;      // chunk-local row
  f64x4 acc00 = {0.,0.,0.,0.}, acc01 = {0.,0.,0.,0.};
  f64x4 acc10 = {0.,0.,0.,0.}, acc11 = {0.,0.,0.,0.};
  double ref00 = 0., ref01 = 0., ref10 = 0., ref40 = 0., ref04 = 0.;
  const size_t xrow0 = (size_t)b0 * 1024 + m0;

  for (int k0t = 0; k0t < 1024; k0t += 16) {
    __syncthreads();
    {
      int r = t >> 2, kq = (t & 3) << 2;
      float4 xv = *(const float4*)&X[(xrow0 + r) * 1024 + k0t + kq];
      As[kq + 0][r] = (double)xv.x;
      As[kq + 1][r] = (double)xv.y;
      As[kq + 2][r] = (double)xv.z;
      As[kq + 3][r] = (double)xv.w;
      int kr = t >> 4, cq = (t & 15) << 2;
      float4 wv = *(const float4*)&W[(size_t)(k0t + kr) * 3072 + n0 + cq];
      Bs[kr][cq + 0] = (double)wv.x;
      Bs[kr][cq + 1] = (double)wv.y;
      Bs[kr][cq + 2] = (double)wv.z;
      Bs[kr][cq + 3] = (double)wv.w;
    }
    __syncthreads();
#pragma unroll
    for (int k0 = 0; k0 < 16; k0 += 4) {
      double a0 = As[k0 + l4][m0w + lm];
      double a1 = As[k0 + l4][m0w + 16 + lm];
      double bb0 = Bs[k0 + l4][n0w + lm];
      double bb1 = Bs[k0 + l4][n0w + 16 + lm];
      acc00 = __builtin_amdgcn_mfma_f64_16x16x4f64(a0, bb0, acc00, 0, 0, 0);
      acc01 = __builtin_amdgcn_mfma_f64_16x16x4f64(a0, bb1, acc01, 0, 0, 0);
      acc10 = __builtin_amdgcn_mfma_f64_16x16x4f64(a1, bb0, acc10, 0, 0, 0);
      acc11 = __builtin_amdgcn_mfma_f64_16x16x4f64(a1, bb1, acc11, 0, 0, 0);
    }
    // calibration refs (this wave's tile; ~cheap, broadcast LDS reads)
#pragma unroll
    for (int kk = 0; kk < 16; ++kk) {
      double b0v = Bs[kk][n0w], b1v = Bs[kk][n0w + 1], b4v = Bs[kk][n0w + 4];
      double a0v = As[kk][m0w], a1v = As[kk][m0w + 1], a4v = As[kk][m0w + 4];
      ref00 = fma(a0v, b0v, ref00);
      ref01 = fma(a0v, b1v, ref01);
      ref10 = fma(a1v, b0v, ref10);
      ref40 = fma(a4v, b0v, ref40);
      ref04 = fma(a0v, b4v, ref04);
    }
  }

  // ---- layout detection (wave 0 decides; block-uniform broadcast) ----
  double v00 = __shfl(acc00[0], 0);
  double v16 = __shfl(acc00[0], 16);
  if (t == 0) {
    int m;
    if (fabs(v00 - ref00) > 1e-5) {
      m = 0;                                   // A/B model wrong -> fallback
    } else {
      double d1 = fabs(v16 - ref40);           // C1: lane16,reg0 = D[4][0]
      double d2 = fabs(v16 - ref10);           // C2: D[1][0]
      double d3 = fabs(v16 - ref04);           // C3: D[0][4]
      double d4 = fabs(v16 - ref01);           // C4: D[0][1]
      m = 1; double best = d1;
      if (d2 < best) { best = d2; m = 2; }
      if (d3 < best) { best = d3; m = 3; }
      if (d4 < best) { best = d4; m = 4; }
    }
    s_mode = m;
  }
  __syncthreads();
  const int mode = s_mode;

  double* T = (n0 < 1024) ? qT : kT;
  const int nn = n0 & 1023;
  const int h = nn >> 6;
  const int bl = m0 >> 10;
  const int sb = m0 & 1023;
  const size_t hb = (size_t)(bl * 16 + h) * 64;

  if (mode != 0) {
#pragma unroll
    for (int ni = 0; ni < 2; ++ni) {
#pragma unroll
      for (int mi = 0; mi < 2; ++mi) {
        f64x4 av = ni ? (mi ? acc11 : acc01) : (mi ? acc10 : acc00);
        if (mode <= 2) {
          const int d = n0w + 16 * ni + lm;
          const double bz = (double)bias[n0 + d];
          const size_t cb = ((hb + d) << 10) + sb;
#pragma unroll
          for (int r = 0; r < 4; ++r) {
            int row = m0w + 16 * mi + ((mode == 1) ? (4 * l4 + r) : (l4 + 4 * r));
            T[cb + row] = av[r] + bz;
          }
        } else {
          const int row = m0w + 16 * mi + lm;
#pragma unroll
          for (int r = 0; r < 4; ++r) {
            int d = n0w + 16 * ni + ((mode == 3) ? (4 * l4 + r) : (l4 + 4 * r));
            T[((hb + d) << 10) + sb + row] = av[r] + (double)bias[n0 + d];
          }
        }
      }
    }
  } else {
    // ---- VALU fallback: recompute the whole tile (guaranteed correct) ----
    double accv[2][8];
#pragma unroll
    for (int i = 0; i < 2; ++i)
#pragma unroll
      for (int j = 0; j < 8; ++j) accv[i][j] = 0.;
    for (int k0t = 0; k0t < 1024; k0t += 16) {
      __syncthreads();
      {
        int r = t >> 2, kq = (t & 3) << 2;
        float4 xv = *(const float4*)&X[(xrow0 + r) * 1024 + k0t + kq];
        As[kq + 0][r] = (double)xv.x;
        As[kq + 1][r] = (double)xv.y;
        As[kq + 2][r] = (double)xv.z;
        As[kq + 3][r] = (double)xv.w;
        int kr = t >> 4, cq = (t & 15) << 2;
        float4 wv = *(const float4*)&W[(size_t)(k0t + kr) * 3072 + n0 + cq];
        Bs[kr][cq + 0] = (double)wv.x;
        Bs[kr][cq + 1] = (double)wv.y;
        Bs[kr][cq + 2] = (double)wv.z;
        Bs[kr][cq + 3] = (double)wv.w;
      }
      __syncthreads();
#pragma unroll
      for (int kk = 0; kk < 16; ++kk) {
        double a0 = As[kk][m0w + lm];
        double a1 = As[kk][m0w + 16 + lm];
#pragma unroll
        for (int j = 0; j < 8; ++j) {
          double bb = Bs[kk][n0w + 8 * l4 + j];
          accv[0][j] = fma(a0, bb, accv[0][j]);
          accv[1][j] = fma(a1, bb, accv[1][j]);
        }
      }
    }
#pragma unroll
    for (int j = 0; j < 8; ++j) {
      const int d = n0w + 8 * l4 + j;
      const double bz = (double)bias[n0 + d];
      const size_t cb = ((hb + d) << 10) + sb;
      T[cb + m0w + lm]      = accv[0][j] + bz;
      T[cb + m0w + 16 + lm] = accv[1][j] + bz;
    }
  }
}

// ---------------- K2: v GEMM fp32, 128x128 tile (unchanged) ----------------
__global__ __launch_bounds__(256) void v_gemm_f32(
    const float* __restrict__ X, const float* __restrict__ W,
    const float* __restrict__ bias, float* __restrict__ Vp, int b0)
{
  __shared__ __align__(16) float As[16][132];
  __shared__ __align__(16) float Bs[16][132];
  const int t = threadIdx.x, tx = t & 15, ty = t >> 4;
  const int n0 = blockIdx.x * 128;
  const int m0 = blockIdx.y * 128;
  float acc[2][2][4][4] = {};
  const size_t xrow0 = (size_t)b0 * 1024 + m0;

  for (int k0 = 0; k0 < 1024; k0 += 16) {
    __syncthreads();
#pragma unroll
    for (int p = 0; p < 2; ++p) {
      int f = p * 256 + t;
      int r = f >> 2, kq = (f & 3) << 2;
      float4 xv = *(const float4*)&X[(xrow0 + r) * 1024 + k0 + kq];
      As[kq + 0][r] = xv.x; As[kq + 1][r] = xv.y;
      As[kq + 2][r] = xv.z; As[kq + 3][r] = xv.w;
      int kr = f >> 5, cq = (f & 31) << 2;
      *(float4*)&Bs[kr][cq] = *(const float4*)&W[(size_t)(k0 + kr) * 3072 + 2048 + n0 + cq];
    }
    __syncthreads();
#pragma unroll
    for (int kk = 0; kk < 16; ++kk) {
      float4 A0 = *(const float4*)&As[kk][4 * ty];
      float4 A1 = *(const float4*)&As[kk][64 + 4 * ty];
      float4 B0 = *(const float4*)&Bs[kk][4 * tx];
      float4 B1 = *(const float4*)&Bs[kk][64 + 4 * tx];
      float a[2][4] = {{A0.x, A0.y, A0.z, A0.w}, {A1.x, A1.y, A1.z, A1.w}};
      float b[2][4] = {{B0.x, B0.y, B0.z, B0.w}, {B1.x, B1.y, B1.z, B1.w}};
#pragma unroll
      for (int ri = 0; ri < 2; ++ri)
#pragma unroll
        for (int i = 0; i < 4; ++i)
#pragma unroll
          for (int ci = 0; ci < 2; ++ci)
#pragma unroll
            for (int j = 0; j < 4; ++j)
              acc[ri][ci][i][j] = fmaf(a[ri][i], b[ci][j], acc[ri][ci][i][j]);
    }
  }
  const int bl = m0 >> 10;
  const int sb = m0 & 1023;
#pragma unroll
  for (int ci = 0; ci < 2; ++ci) {
    int h = (n0 >> 6) + ci;
    float bz[4];
#pragma unroll
    for (int j = 0; j < 4; ++j) bz[j] = bias[2048 + n0 + 64 * ci + 4 * tx + j];
#pragma unroll
    for (int ri = 0; ri < 2; ++ri)
#pragma unroll
      for (int i = 0; i < 4; ++i) {
        int s = sb + 64 * ri + 4 * ty + i;
        float4 vv = make_float4(acc[ri][ci][i][0] + bz[0], acc[ri][ci][i][1] + bz[1],
                                acc[ri][ci][i][2] + bz[2], acc[ri][ci][i][3] + bz[3]);
        *(float4*)&Vp[((size_t)(bl * 16 + h) * 1024 + s) * 64 + 4 * tx] = vv;
      }
  }
}

// ---------------- K3: fused attention v2 (unchanged) ----------------
__global__ __launch_bounds__(256) void attn_fused(
    const double* __restrict__ qT, const double* __restrict__ kT,
    const float* __restrict__ Vp, const float* __restrict__ Mask,
    float* __restrict__ AO, int b0)
{
  __shared__ double Qs[64][64];
  __shared__ double KVd[64][64];
  const int t = threadIdx.x, tx = t & 15, ty = t >> 4;
  const int bh = blockIdx.y;
  const int bl = bh >> 4, h = bh & 15;
  const int bg = b0 + bl;
  const int q0 = blockIdx.x * 64;
  const double* qTb = qT + (size_t)bh * 65536;
  const double* kTb = kT + (size_t)bh * 65536;
  const float*  Vb  = Vp + (size_t)bh * 65536;
  const float*  mb  = Mask + (size_t)bg * 1048576 + (size_t)q0 * 1024;
  float* Ps = (float*)&KVd[0][0];
  float* Vf = (float*)((char*)&KVd[0][0] + 16384);

#pragma unroll
  for (int p = 0; p < 8; ++p) {
    int f = p * 256 + t;
    int d = f >> 5, c = f & 31;
    *(double2*)&Qs[d][2 * c] = *(const double2*)&qTb[(size_t)d * 1024 + q0 + 2 * c];
  }

  double Mreg[4] = {-1e300, -1e300, -1e300, -1e300};
  float Lreg[4] = {0.f, 0.f, 0.f, 0.f};
  float o[4][4] = {};

  for (int kt = 0; kt < 16; ++kt) {
    const int k0 = kt * 64;
    __syncthreads();
#pragma unroll
    for (int p = 0; p < 8; ++p) {
      int f = p * 256 + t;
      int d = f >> 5, c = f & 31;
      *(double2*)&KVd[d][2 * c] = *(const double2*)&kTb[(size_t)d * 1024 + k0 + 2 * c];
    }
    __syncthreads();
    double s[4][4] = {};
#pragma unroll 4
    for (int d = 0; d < 64; ++d) {
      double2 qa = *(const double2*)&Qs[d][2 * ty];
      double2 qb = *(const double2*)&Qs[d][2 * ty + 32];
      double2 ka = *(const double2*)&KVd[d][2 * tx];
      double2 kb = *(const double2*)&KVd[d][2 * tx + 32];
      double aq[4] = {qa.x, qa.y, qb.x, qb.y};
      double ak[4] = {ka.x, ka.y, kb.x, kb.y};
#pragma unroll
      for (int i = 0; i < 4; ++i)
#pragma unroll
        for (int j = 0; j < 4; ++j)
          s[i][j] = fma(aq[i], ak[j], s[i][j]);
    }
    __syncthreads();
    float al[4];
#pragma unroll
    for (int i = 0; i < 4; ++i) {
      const int qi = 2 * ty + (i & 1) + (i >> 1) * 32;
      float2 m01 = *(const float2*)&mb[(size_t)qi * 1024 + k0 + 2 * tx];
      float2 m23 = *(const float2*)&mb[(size_t)qi * 1024 + k0 + 2 * tx + 32];
      double z0 = (m01.x != 0.f) ? s[i][0] * -1.25e8 : 0.0;
      double z1 = (m01.y != 0.f) ? s[i][1] * -1.25e8 : 0.0;
      double z2 = (m23.x != 0.f) ? s[i][2] * -1.25e8 : 0.0;
      double z3 = (m23.y != 0.f) ? s[i][3] * -1.25e8 : 0.0;
      double mx = fmax(fmax(z0, z1), fmax(z2, z3));
#pragma unroll
      for (int ww = 1; ww < 16; ww <<= 1) mx = fmax(mx, __shfl_xor(mx, ww));
      double nM = fmax(Mreg[i], mx);
      double da = Mreg[i] - nM;
      al[i] = (da < -80.0) ? 0.f : expf((float)da);
      double d0 = z0 - nM, d1 = z1 - nM, d2 = z2 - nM, d3 = z3 - nM;
      float p0 = (d0 < -80.0) ? 0.f : expf((float)d0);
      float p1 = (d1 < -80.0) ? 0.f : expf((float)d1);
      float p2 = (d2 < -80.0) ? 0.f : expf((float)d2);
      float p3 = (d3 < -80.0) ? 0.f : expf((float)d3);
      float ps = ((p0 + p1) + p2) + p3;
#pragma unroll
      for (int ww = 1; ww < 16; ww <<= 1) ps += __shfl_xor(ps, ww);
      Lreg[i] = Lreg[i] * al[i] + ps;
      Mreg[i] = nM;
      *(float2*)&Ps[qi * 64 + 2 * tx] = make_float2(p0, p1);
      *(float2*)&Ps[qi * 64 + 2 * tx + 32] = make_float2(p2, p3);
    }
#pragma unroll
    for (int p = 0; p < 4; ++p) {
      int f = p * 256 + t;
      *(float4*)&Vf[4 * f] = *(const float4*)&Vb[(size_t)k0 * 64 + 4 * f];
    }
    __syncthreads();
#pragma unroll
    for (int i = 0; i < 4; ++i) {
      o[i][0] *= al[i]; o[i][1] *= al[i]; o[i][2] *= al[i]; o[i][3] *= al[i];
    }
#pragma unroll 4
    for (int kk = 0; kk < 64; kk += 4) {
      float4 vv0 = *(const float4*)&Vf[(kk + 0) * 64 + 4 * tx];
      float4 vv1 = *(const float4*)&Vf[(kk + 1) * 64 + 4 * tx];
      float4 vv2 = *(const float4*)&Vf[(kk + 2) * 64 + 4 * tx];
      float4 vv3 = *(const float4*)&Vf[(kk + 3) * 64 + 4 * tx];
#pragma unroll
      for (int i = 0; i < 4; ++i) {
        const int qi = 2 * ty + (i & 1) + (i >> 1) * 32;
        float4 pa = *(const float4*)&Ps[qi * 64 + kk];
        o[i][0] = fmaf(pa.x, vv0.x, o[i][0]);
        o[i][0] = fmaf(pa.y, vv1.x, o[i][0]);
        o[i][0] = fmaf(pa.z, vv2.x, o[i][0]);
        o[i][0] = fmaf(pa.w, vv3.x, o[i][0]);
        o[i][1] = fmaf(pa.x, vv0.y, o[i][1]);
        o[i][1] = fmaf(pa.y, vv1.y, o[i][1]);
        o[i][1] = fmaf(pa.z, vv2.y, o[i][1]);
        o[i][1] = fmaf(pa.w, vv3.y, o[i][1]);
        o[i][2] = fmaf(pa.x, vv0.z, o[i][2]);
        o[i][2] = fmaf(pa.y, vv1.z, o[i][2]);
        o[i][2] = fmaf(pa.z, vv2.z, o[i][2]);
        o[i][2] = fmaf(pa.w, vv3.z, o[i][2]);
        o[i][3] = fmaf(pa.x, vv0.w, o[i][3]);
        o[i][3] = fmaf(pa.y, vv1.w, o[i][3]);
        o[i][3] = fmaf(pa.z, vv2.w, o[i][3]);
        o[i][3] = fmaf(pa.w, vv3.w, o[i][3]);
      }
    }
  }
#pragma unroll
  for (int i = 0; i < 4; ++i) {
    const int qi = 2 * ty + (i & 1) + (i >> 1) * 32;
    float inv = (Lreg[i] > 0.f) ? 1.f / Lreg[i] : 0.f;
    float4 vv = make_float4(o[i][0] * inv, o[i][1] * inv, o[i][2] * inv, o[i][3] * inv);
    *(float4*)&AO[(size_t)(bl * 1024 + q0 + qi) * 1024 + h * 64 + 4 * tx] = vv;
  }
}

// ---------------- K4: output projection fp32 (unchanged) ----------------
__global__ __launch_bounds__(256) void proj_gemm(
    const float* __restrict__ AO, const float* __restrict__ W,
    const float* __restrict__ bias, float* __restrict__ Out, int b0)
{
  __shared__ __align__(16) float As[16][132];
  __shared__ __align__(16) float Bs[16][132];
  const int t = threadIdx.x, tx = t & 15, ty = t >> 4;
  const int n0 = blockIdx.x * 128;
  const int m0l = blockIdx.y * 128;
  float acc[2][2][4][4] = {};

  for (int k0 = 0; k0 < 1024; k0 += 16) {
    __syncthreads();
#pragma unroll
    for (int p = 0; p < 2; ++p) {
      int f = p * 256 + t;
      int r = f >> 2, kq = (f & 3) << 2;
      float4 av = *(const float4*)&AO[(size_t)(m0l + r) * 1024 + k0 + kq];
      As[kq + 0][r] = av.x; As[kq + 1][r] = av.y;
      As[kq + 2][r] = av.z; As[kq + 3][r] = av.w;
      int kr = f >> 5, cq = (f & 31) << 2;
      *(float4*)&Bs[kr][cq] = *(const float4*)&W[(size_t)(k0 + kr) * 1024 + n0 + cq];
    }
    __syncthreads();
#pragma unroll
    for (int kk = 0; kk < 16; ++kk) {
      float4 A0 = *(const float4*)&As[kk][4 * ty];
      float4 A1 = *(const float4*)&As[kk][64 + 4 * ty];
      float4 B0 = *(const float4*)&Bs[kk][4 * tx];
      float4 B1 = *(const float4*)&Bs[kk][64 + 4 * tx];
      float a[2][4] = {{A0.x, A0.y, A0.z, A0.w}, {A1.x, A1.y, A1.z, A1.w}};
      float b[2][4] = {{B0.x, B0.y, B0.z, B0.w}, {B1.x, B1.y, B1.z, B1.w}};
#pragma unroll
      for (int ri = 0; ri < 2; ++ri)
#pragma unroll
        for (int i = 0; i < 4; ++i)
#pragma unroll
          for (int ci = 0; ci < 2; ++ci)
#pragma unroll
            for (int j = 0; j < 4; ++j)
              acc[ri][ci][i][j] = fmaf(a[ri][i], b[ci][j], acc[ri][ci][i][j]);
    }
  }
#pragma unroll
  for (int ci = 0; ci < 2; ++ci) {
    float bz[4];
#pragma unroll
    for (int j = 0; j < 4; ++j) bz[j] = bias[n0 + 64 * ci + 4 * tx + j];
#pragma unroll
    for (int ri = 0; ri < 2; ++ri)
#pragma unroll
      for (int i = 0; i < 4; ++i) {
        float4 vv = make_float4(acc[ri][ci][i][0] + bz[0], acc[ri][ci][i][1] + bz[1],
                                acc[ri][ci][i][2] + bz[2], acc[ri][ci][i][3] + bz[3]);
        size_t row = (size_t)b0 * 1024 + m0l + 64 * ri + 4 * ty + i;
        *(float4*)&Out[row * 1024 + n0 + 64 * ci + 4 * tx] = vv;
      }
  }
}

extern "C" void kernel_launch(void* const* d_in, const int* in_sizes, int n_in,
                              void* d_out, int out_size, void* d_ws, size_t ws_size,
                              hipStream_t stream) {
  (void)in_sizes; (void)n_in; (void)out_size;
  const float* x      = (const float*)d_in[0];
  const float* mask   = (const float*)d_in[1];
  const float* W_attn = (const float*)d_in[2];
  const float* b_attn = (const float*)d_in[3];
  const float* W_proj = (const float*)d_in[4];
  const float* b_proj = (const float*)d_in[5];
  float* out = (float*)d_out;

  int CB = (ws_size >= (192ull << 20)) ? 8
         : (ws_size >= (96ull  << 20)) ? 4
         : (ws_size >= (48ull  << 20)) ? 2 : 1;

  char* base = (char*)d_ws;
  double* qT = (double*)base;
  double* kT = (double*)(base + (size_t)CB * (8ull  << 20));
  float*  Vp = (float*)(base + (size_t)CB * (16ull << 20));
  float*  AO = (float*)(base + (size_t)CB * (20ull << 20));

  for (int b0 = 0; b0 < 8; b0 += CB) {
    qk_gemm_f64<<<dim3(32, 16 * CB), 256, 0, stream>>>(x, W_attn, b_attn, qT, kT, b0);
    v_gemm_f32<<<dim3(8, 8 * CB), 256, 0, stream>>>(x, W_attn, b_attn, Vp, b0);
    attn_fused<<<dim3(16, 16 * CB), 256, 0, stream>>>(qT, kT, Vp, mask, AO, b0);
    proj_gemm<<<dim3(8, 8 * CB), 256, 0, stream>>>(AO, W_proj, b_proj, out, b0);
  }
}

// Round 24
// 1793.890 us; speedup vs baseline: 1.2792x; 1.2039x over previous
//
#include <hip/hip_runtime.h>
#include <math.h>

// ROUND 24: hoist f64-MFMA layout calibration out of the hot loop.
// r23 self-calibrated per-block-per-K-tile (~2x inner-loop overhead:
// VALUBusy 29% on top of MfmaUtil 43.5%). Now a one-wave pre-kernel runs the
// identical detection once on the first 64x64x16 tile and publishes the mode
// via a 4-byte __device__ global; the main kernel reads it as a uniform
// scalar. Same mode-switched store + VALU fallback. attn/v_gemm/proj frozen.

typedef double f64x4 __attribute__((ext_vector_type(4)));

__device__ int g_qk_mode;

// ---------------- K0: one-wave layout calibration ----------------
__global__ void qk_calib(const float* __restrict__ X, const float* __restrict__ W)
{
  __shared__ double As[16][66];
  __shared__ double Bs[16][66];
  const int t = threadIdx.x;            // 64 threads = 1 wave
  const int lm = t & 15, l4 = t >> 4;
  // stage first tile: A = X[m=0..63][k=0..15], B = W[k=0..15][n=0..63]
  for (int p = 0; p < 16; ++p) {
    int f = p * 64 + t;
    int k = f >> 6, m = f & 63;
    As[k][m] = (double)X[(size_t)m * 1024 + k];
    Bs[k][m] = (double)W[(size_t)k * 3072 + m];
  }
  __syncthreads();
  f64x4 acc = {0., 0., 0., 0.};
#pragma unroll
  for (int k0 = 0; k0 < 16; k0 += 4) {
    double a = As[k0 + l4][lm];
    double b = Bs[k0 + l4][lm];
    acc = __builtin_amdgcn_mfma_f64_16x16x4f64(a, b, acc, 0, 0, 0);
  }
  double ref00 = 0., ref01 = 0., ref10 = 0., ref40 = 0., ref04 = 0.;
#pragma unroll
  for (int kk = 0; kk < 16; ++kk) {
    double a0 = As[kk][0], a1 = As[kk][1], a4 = As[kk][4];
    double b0 = Bs[kk][0], b1 = Bs[kk][1], b4 = Bs[kk][4];
    ref00 = fma(a0, b0, ref00);
    ref01 = fma(a0, b1, ref01);
    ref10 = fma(a1, b0, ref10);
    ref40 = fma(a4, b0, ref40);
    ref04 = fma(a0, b4, ref04);
  }
  double v00 = __shfl(acc[0], 0);
  double v16 = __shfl(acc[0], 16);
  if (t == 0) {
    int m;
    if (fabs(v00 - ref00) > 1e-5) {
      m = 0;                                   // model wrong -> VALU fallback
    } else {
      double d1 = fabs(v16 - ref40);           // mode1: D row = 4*l4+r
      double d2 = fabs(v16 - ref10);           // mode2: D row = l4+4*r
      double d3 = fabs(v16 - ref04);           // mode3: transposed, col = 4*l4+r
      double d4 = fabs(v16 - ref01);           // mode4: transposed, col = l4+4*r
      m = 1; double best = d1;
      if (d2 < best) { best = d2; m = 2; }
      if (d3 < best) { best = d3; m = 3; }
      if (d4 < best) { best = d4; m = 4; }
    }
    g_qk_mode = m;
  }
}

// ---------------- K1: q,k GEMM fp64 MFMA (mode from g_qk_mode) ----------------
__global__ __launch_bounds__(256) void qk_gemm_f64(
    const float* __restrict__ X, const float* __restrict__ W,
    const float* __restrict__ bias,
    double* __restrict__ qT, double* __restrict__ kT, int b0)
{
  __shared__ double As[16][66];   // [k][m]
  __shared__ double Bs[16][66];   // [k][n]
  const int t = threadIdx.x;
  const int lane = t & 63, w = t >> 6;        // 4 waves
  const int lm = lane & 15, l4 = lane >> 4;
  const int m0w = (w & 1) * 32, n0w = (w >> 1) * 32;
  const int n0 = blockIdx.x * 64;      // 0..2047
  const int m0 = blockIdx.y * 64;      // chunk-local row
  const int mode = g_qk_mode;          // uniform scalar
  f64x4 acc00 = {0.,0.,0.,0.}, acc01 = {0.,0.,0.,0.};
  f64x4 acc10 = {0.,0.,0.,0.}, acc11 = {0.,0.,0.,0.};
  const size_t xrow0 = (size_t)b0 * 1024 + m0;

  if (mode != 0) {
    for (int k0t = 0; k0t < 1024; k0t += 16) {
      __syncthreads();
      {
        int r = t >> 2, kq = (t & 3) << 2;
        float4 xv = *(const float4*)&X[(xrow0 + r) * 1024 + k0t + kq];
        As[kq + 0][r] = (double)xv.x;
        As[kq + 1][r] = (double)xv.y;
        As[kq + 2][r] = (double)xv.z;
        As[kq + 3][r] = (double)xv.w;
        int kr = t >> 4, cq = (t & 15) << 2;
        float4 wv = *(const float4*)&W[(size_t)(k0t + kr) * 3072 + n0 + cq];
        Bs[kr][cq + 0] = (double)wv.x;
        Bs[kr][cq + 1] = (double)wv.y;
        Bs[kr][cq + 2] = (double)wv.z;
        Bs[kr][cq + 3] = (double)wv.w;
      }
      __syncthreads();
#pragma unroll
      for (int k0 = 0; k0 < 16; k0 += 4) {
        double a0 = As[k0 + l4][m0w + lm];
        double a1 = As[k0 + l4][m0w + 16 + lm];
        double bb0 = Bs[k0 + l4][n0w + lm];
        double bb1 = Bs[k0 + l4][n0w + 16 + lm];
        acc00 = __builtin_amdgcn_mfma_f64_16x16x4f64(a0, bb0, acc00, 0, 0, 0);
        acc01 = __builtin_amdgcn_mfma_f64_16x16x4f64(a0, bb1, acc01, 0, 0, 0);
        acc10 = __builtin_amdgcn_mfma_f64_16x16x4f64(a1, bb0, acc10, 0, 0, 0);
        acc11 = __builtin_amdgcn_mfma_f64_16x16x4f64(a1, bb1, acc11, 0, 0, 0);
      }
    }
  }

  double* T = (n0 < 1024) ? qT : kT;
  const int nn = n0 & 1023;
  const int h = nn >> 6;
  const int bl = m0 >> 10;
  const int sb = m0 & 1023;
  const size_t hb = (size_t)(bl * 16 + h) * 64;

  if (mode != 0) {
#pragma unroll
    for (int ni = 0; ni < 2; ++ni) {
#pragma unroll
      for (int mi = 0; mi < 2; ++mi) {
        f64x4 av = ni ? (mi ? acc11 : acc01) : (mi ? acc10 : acc00);
        if (mode <= 2) {
          const int d = n0w + 16 * ni + lm;
          const double bz = (double)bias[n0 + d];
          const size_t cb = ((hb + d) << 10) + sb;
#pragma unroll
          for (int r = 0; r < 4; ++r) {
            int row = m0w + 16 * mi + ((mode == 1) ? (4 * l4 + r) : (l4 + 4 * r));
            T[cb + row] = av[r] + bz;
          }
        } else {
          const int row = m0w + 16 * mi + lm;
#pragma unroll
          for (int r = 0; r < 4; ++r) {
            int d = n0w + 16 * ni + ((mode == 3) ? (4 * l4 + r) : (l4 + 4 * r));
            T[((hb + d) << 10) + sb + row] = av[r] + (double)bias[n0 + d];
          }
        }
      }
    }
  } else {
    // ---- VALU fallback: recompute the whole tile (guaranteed correct) ----
    double accv[2][8];
#pragma unroll
    for (int i = 0; i < 2; ++i)
#pragma unroll
      for (int j = 0; j < 8; ++j) accv[i][j] = 0.;
    for (int k0t = 0; k0t < 1024; k0t += 16) {
      __syncthreads();
      {
        int r = t >> 2, kq = (t & 3) << 2;
        float4 xv = *(const float4*)&X[(xrow0 + r) * 1024 + k0t + kq];
        As[kq + 0][r] = (double)xv.x;
        As[kq + 1][r] = (double)xv.y;
        As[kq + 2][r] = (double)xv.z;
        As[kq + 3][r] = (double)xv.w;
        int kr = t >> 4, cq = (t & 15) << 2;
        float4 wv = *(const float4*)&W[(size_t)(k0t + kr) * 3072 + n0 + cq];
        Bs[kr][cq + 0] = (double)wv.x;
        Bs[kr][cq + 1] = (double)wv.y;
        Bs[kr][cq + 2] = (double)wv.z;
        Bs[kr][cq + 3] = (double)wv.w;
      }
      __syncthreads();
#pragma unroll
      for (int kk = 0; kk < 16; ++kk) {
        double a0 = As[kk][m0w + lm];
        double a1 = As[kk][m0w + 16 + lm];
#pragma unroll
        for (int j = 0; j < 8; ++j) {
          double bb = Bs[kk][n0w + 8 * l4 + j];
          accv[0][j] = fma(a0, bb, accv[0][j]);
          accv[1][j] = fma(a1, bb, accv[1][j]);
        }
      }
    }
#pragma unroll
    for (int j = 0; j < 8; ++j) {
      const int d = n0w + 8 * l4 + j;
      const double bz = (double)bias[n0 + d];
      const size_t cb = ((hb + d) << 10) + sb;
      T[cb + m0w + lm]      = accv[0][j] + bz;
      T[cb + m0w + 16 + lm] = accv[1][j] + bz;
    }
  }
}

// ---------------- K2: v GEMM fp32, 128x128 tile (unchanged) ----------------
__global__ __launch_bounds__(256) void v_gemm_f32(
    const float* __restrict__ X, const float* __restrict__ W,
    const float* __restrict__ bias, float* __restrict__ Vp, int b0)
{
  __shared__ __align__(16) float As[16][132];
  __shared__ __align__(16) float Bs[16][132];
  const int t = threadIdx.x, tx = t & 15, ty = t >> 4;
  const int n0 = blockIdx.x * 128;
  const int m0 = blockIdx.y * 128;
  float acc[2][2][4][4] = {};
  const size_t xrow0 = (size_t)b0 * 1024 + m0;

  for (int k0 = 0; k0 < 1024; k0 += 16) {
    __syncthreads();
#pragma unroll
    for (int p = 0; p < 2; ++p) {
      int f = p * 256 + t;
      int r = f >> 2, kq = (f & 3) << 2;
      float4 xv = *(const float4*)&X[(xrow0 + r) * 1024 + k0 + kq];
      As[kq + 0][r] = xv.x; As[kq + 1][r] = xv.y;
      As[kq + 2][r] = xv.z; As[kq + 3][r] = xv.w;
      int kr = f >> 5, cq = (f & 31) << 2;
      *(float4*)&Bs[kr][cq] = *(const float4*)&W[(size_t)(k0 + kr) * 3072 + 2048 + n0 + cq];
    }
    __syncthreads();
#pragma unroll
    for (int kk = 0; kk < 16; ++kk) {
      float4 A0 = *(const float4*)&As[kk][4 * ty];
      float4 A1 = *(const float4*)&As[kk][64 + 4 * ty];
      float4 B0 = *(const float4*)&Bs[kk][4 * tx];
      float4 B1 = *(const float4*)&Bs[kk][64 + 4 * tx];
      float a[2][4] = {{A0.x, A0.y, A0.z, A0.w}, {A1.x, A1.y, A1.z, A1.w}};
      float b[2][4] = {{B0.x, B0.y, B0.z, B0.w}, {B1.x, B1.y, B1.z, B1.w}};
#pragma unroll
      for (int ri = 0; ri < 2; ++ri)
#pragma unroll
        for (int i = 0; i < 4; ++i)
#pragma unroll
          for (int ci = 0; ci < 2; ++ci)
#pragma unroll
            for (int j = 0; j < 4; ++j)
              acc[ri][ci][i][j] = fmaf(a[ri][i], b[ci][j], acc[ri][ci][i][j]);
    }
  }
  const int bl = m0 >> 10;
  const int sb = m0 & 1023;
#pragma unroll
  for (int ci = 0; ci < 2; ++ci) {
    int h = (n0 >> 6) + ci;
    float bz[4];
#pragma unroll
    for (int j = 0; j < 4; ++j) bz[j] = bias[2048 + n0 + 64 * ci + 4 * tx + j];
#pragma unroll
    for (int ri = 0; ri < 2; ++ri)
#pragma unroll
      for (int i = 0; i < 4; ++i) {
        int s = sb + 64 * ri + 4 * ty + i;
        float4 vv = make_float4(acc[ri][ci][i][0] + bz[0], acc[ri][ci][i][1] + bz[1],
                                acc[ri][ci][i][2] + bz[2], acc[ri][ci][i][3] + bz[3]);
        *(float4*)&Vp[((size_t)(bl * 16 + h) * 1024 + s) * 64 + 4 * tx] = vv;
      }
  }
}

// ---------------- K3: fused attention v2 (unchanged) ----------------
__global__ __launch_bounds__(256) void attn_fused(
    const double* __restrict__ qT, const double* __restrict__ kT,
    const float* __restrict__ Vp, const float* __restrict__ Mask,
    float* __restrict__ AO, int b0)
{
  __shared__ double Qs[64][64];
  __shared__ double KVd[64][64];
  const int t = threadIdx.x, tx = t & 15, ty = t >> 4;
  const int bh = blockIdx.y;
  const int bl = bh >> 4, h = bh & 15;
  const int bg = b0 + bl;
  const int q0 = blockIdx.x * 64;
  const double* qTb = qT + (size_t)bh * 65536;
  const double* kTb = kT + (size_t)bh * 65536;
  const float*  Vb  = Vp + (size_t)bh * 65536;
  const float*  mb  = Mask + (size_t)bg * 1048576 + (size_t)q0 * 1024;
  float* Ps = (float*)&KVd[0][0];
  float* Vf = (float*)((char*)&KVd[0][0] + 16384);

#pragma unroll
  for (int p = 0; p < 8; ++p) {
    int f = p * 256 + t;
    int d = f >> 5, c = f & 31;
    *(double2*)&Qs[d][2 * c] = *(const double2*)&qTb[(size_t)d * 1024 + q0 + 2 * c];
  }

  double Mreg[4] = {-1e300, -1e300, -1e300, -1e300};
  float Lreg[4] = {0.f, 0.f, 0.f, 0.f};
  float o[4][4] = {};

  for (int kt = 0; kt < 16; ++kt) {
    const int k0 = kt * 64;
    __syncthreads();
#pragma unroll
    for (int p = 0; p < 8; ++p) {
      int f = p * 256 + t;
      int d = f >> 5, c = f & 31;
      *(double2*)&KVd[d][2 * c] = *(const double2*)&kTb[(size_t)d * 1024 + k0 + 2 * c];
    }
    __syncthreads();
    double s[4][4] = {};
#pragma unroll 4
    for (int d = 0; d < 64; ++d) {
      double2 qa = *(const double2*)&Qs[d][2 * ty];
      double2 qb = *(const double2*)&Qs[d][2 * ty + 32];
      double2 ka = *(const double2*)&KVd[d][2 * tx];
      double2 kb = *(const double2*)&KVd[d][2 * tx + 32];
      double aq[4] = {qa.x, qa.y, qb.x, qb.y};
      double ak[4] = {ka.x, ka.y, kb.x, kb.y};
#pragma unroll
      for (int i = 0; i < 4; ++i)
#pragma unroll
        for (int j = 0; j < 4; ++j)
          s[i][j] = fma(aq[i], ak[j], s[i][j]);
    }
    __syncthreads();
    float al[4];
#pragma unroll
    for (int i = 0; i < 4; ++i) {
      const int qi = 2 * ty + (i & 1) + (i >> 1) * 32;
      float2 m01 = *(const float2*)&mb[(size_t)qi * 1024 + k0 + 2 * tx];
      float2 m23 = *(const float2*)&mb[(size_t)qi * 1024 + k0 + 2 * tx + 32];
      double z0 = (m01.x != 0.f) ? s[i][0] * -1.25e8 : 0.0;
      double z1 = (m01.y != 0.f) ? s[i][1] * -1.25e8 : 0.0;
      double z2 = (m23.x != 0.f) ? s[i][2] * -1.25e8 : 0.0;
      double z3 = (m23.y != 0.f) ? s[i][3] * -1.25e8 : 0.0;
      double mx = fmax(fmax(z0, z1), fmax(z2, z3));
#pragma unroll
      for (int ww = 1; ww < 16; ww <<= 1) mx = fmax(mx, __shfl_xor(mx, ww));
      double nM = fmax(Mreg[i], mx);
      double da = Mreg[i] - nM;
      al[i] = (da < -80.0) ? 0.f : expf((float)da);
      double d0 = z0 - nM, d1 = z1 - nM, d2 = z2 - nM, d3 = z3 - nM;
      float p0 = (d0 < -80.0) ? 0.f : expf((float)d0);
      float p1 = (d1 < -80.0) ? 0.f : expf((float)d1);
      float p2 = (d2 < -80.0) ? 0.f : expf((float)d2);
      float p3 = (d3 < -80.0) ? 0.f : expf((float)d3);
      float ps = ((p0 + p1) + p2) + p3;
#pragma unroll
      for (int ww = 1; ww < 16; ww <<= 1) ps += __shfl_xor(ps, ww);
      Lreg[i] = Lreg[i] * al[i] + ps;
      Mreg[i] = nM;
      *(float2*)&Ps[qi * 64 + 2 * tx] = make_float2(p0, p1);
      *(float2*)&Ps[qi * 64 + 2 * tx + 32] = make_float2(p2, p3);
    }
#pragma unroll
    for (int p = 0; p < 4; ++p) {
      int f = p * 256 + t;
      *(float4*)&Vf[4 * f] = *(const float4*)&Vb[(size_t)k0 * 64 + 4 * f];
    }
    __syncthreads();
#pragma unroll
    for (int i = 0; i < 4; ++i) {
      o[i][0] *= al[i]; o[i][1] *= al[i]; o[i][2] *= al[i]; o[i][3] *= al[i];
    }
#pragma unroll 4
    for (int kk = 0; kk < 64; kk += 4) {
      float4 vv0 = *(const float4*)&Vf[(kk + 0) * 64 + 4 * tx];
      float4 vv1 = *(const float4*)&Vf[(kk + 1) * 64 + 4 * tx];
      float4 vv2 = *(const float4*)&Vf[(kk + 2) * 64 + 4 * tx];
      float4 vv3 = *(const float4*)&Vf[(kk + 3) * 64 + 4 * tx];
#pragma unroll
      for (int i = 0; i < 4; ++i) {
        const int qi = 2 * ty + (i & 1) + (i >> 1) * 32;
        float4 pa = *(const float4*)&Ps[qi * 64 + kk];
        o[i][0] = fmaf(pa.x, vv0.x, o[i][0]);
        o[i][0] = fmaf(pa.y, vv1.x, o[i][0]);
        o[i][0] = fmaf(pa.z, vv2.x, o[i][0]);
        o[i][0] = fmaf(pa.w, vv3.x, o[i][0]);
        o[i][1] = fmaf(pa.x, vv0.y, o[i][1]);
        o[i][1] = fmaf(pa.y, vv1.y, o[i][1]);
        o[i][1] = fmaf(pa.z, vv2.y, o[i][1]);
        o[i][1] = fmaf(pa.w, vv3.y, o[i][1]);
        o[i][2] = fmaf(pa.x, vv0.z, o[i][2]);
        o[i][2] = fmaf(pa.y, vv1.z, o[i][2]);
        o[i][2] = fmaf(pa.z, vv2.z, o[i][2]);
        o[i][2] = fmaf(pa.w, vv3.z, o[i][2]);
        o[i][3] = fmaf(pa.x, vv0.w, o[i][3]);
        o[i][3] = fmaf(pa.y, vv1.w, o[i][3]);
        o[i][3] = fmaf(pa.z, vv2.w, o[i][3]);
        o[i][3] = fmaf(pa.w, vv3.w, o[i][3]);
      }
    }
  }
#pragma unroll
  for (int i = 0; i < 4; ++i) {
    const int qi = 2 * ty + (i & 1) + (i >> 1) * 32;
    float inv = (Lreg[i] > 0.f) ? 1.f / Lreg[i] : 0.f;
    float4 vv = make_float4(o[i][0] * inv, o[i][1] * inv, o[i][2] * inv, o[i][3] * inv);
    *(float4*)&AO[(size_t)(bl * 1024 + q0 + qi) * 1024 + h * 64 + 4 * tx] = vv;
  }
}

// ---------------- K4: output projection fp32 (unchanged) ----------------
__global__ __launch_bounds__(256) void proj_gemm(
    const float* __restrict__ AO, const float* __restrict__ W,
    const float* __restrict__ bias, float* __restrict__ Out, int b0)
{
  __shared__ __align__(16) float As[16][132];
  __shared__ __align__(16) float Bs[16][132];
  const int t = threadIdx.x, tx = t & 15, ty = t >> 4;
  const int n0 = blockIdx.x * 128;
  const int m0l = blockIdx.y * 128;
  float acc[2][2][4][4] = {};

  for (int k0 = 0; k0 < 1024; k0 += 16) {
    __syncthreads();
#pragma unroll
    for (int p = 0; p < 2; ++p) {
      int f = p * 256 + t;
      int r = f >> 2, kq = (f & 3) << 2;
      float4 av = *(const float4*)&AO[(size_t)(m0l + r) * 1024 + k0 + kq];
      As[kq + 0][r] = av.x; As[kq + 1][r] = av.y;
      As[kq + 2][r] = av.z; As[kq + 3][r] = av.w;
      int kr = f >> 5, cq = (f & 31) << 2;
      *(float4*)&Bs[kr][cq] = *(const float4*)&W[(size_t)(k0 + kr) * 1024 + n0 + cq];
    }
    __syncthreads();
#pragma unroll
    for (int kk = 0; kk < 16; ++kk) {
      float4 A0 = *(const float4*)&As[kk][4 * ty];
      float4 A1 = *(const float4*)&As[kk][64 + 4 * ty];
      float4 B0 = *(const float4*)&Bs[kk][4 * tx];
      float4 B1 = *(const float4*)&Bs[kk][64 + 4 * tx];
      float a[2][4] = {{A0.x, A0.y, A0.z, A0.w}, {A1.x, A1.y, A1.z, A1.w}};
      float b[2][4] = {{B0.x, B0.y, B0.z, B0.w}, {B1.x, B1.y, B1.z, B1.w}};
#pragma unroll
      for (int ri = 0; ri < 2; ++ri)
#pragma unroll
        for (int i = 0; i < 4; ++i)
#pragma unroll
          for (int ci = 0; ci < 2; ++ci)
#pragma unroll
            for (int j = 0; j < 4; ++j)
              acc[ri][ci][i][j] = fmaf(a[ri][i], b[ci][j], acc[ri][ci][i][j]);
    }
  }
#pragma unroll
  for (int ci = 0; ci < 2; ++ci) {
    float bz[4];
#pragma unroll
    for (int j = 0; j < 4; ++j) bz[j] = bias[n0 + 64 * ci + 4 * tx + j];
#pragma unroll
    for (int ri = 0; ri < 2; ++ri)
#pragma unroll
      for (int i = 0; i < 4; ++i) {
        float4 vv = make_float4(acc[ri][ci][i][0] + bz[0], acc[ri][ci][i][1] + bz[1],
                                acc[ri][ci][i][2] + bz[2], acc[ri][ci][i][3] + bz[3]);
        size_t row = (size_t)b0 * 1024 + m0l + 64 * ri + 4 * ty + i;
        *(float4*)&Out[row * 1024 + n0 + 64 * ci + 4 * tx] = vv;
      }
  }
}

extern "C" void kernel_launch(void* const* d_in, const int* in_sizes, int n_in,
                              void* d_out, int out_size, void* d_ws, size_t ws_size,
                              hipStream_t stream) {
  (void)in_sizes; (void)n_in; (void)out_size;
  const float* x      = (const float*)d_in[0];
  const float* mask   = (const float*)d_in[1];
  const float* W_attn = (const float*)d_in[2];
  const float* b_attn = (const float*)d_in[3];
  const float* W_proj = (const float*)d_in[4];
  const float* b_proj = (const float*)d_in[5];
  float* out = (float*)d_out;

  int CB = (ws_size >= (192ull << 20)) ? 8
         : (ws_size >= (96ull  << 20)) ? 4
         : (ws_size >= (48ull  << 20)) ? 2 : 1;

  char* base = (char*)d_ws;
  double* qT = (double*)base;
  double* kT = (double*)(base + (size_t)CB * (8ull  << 20));
  float*  Vp = (float*)(base + (size_t)CB * (16ull << 20));
  float*  AO = (float*)(base + (size_t)CB * (20ull << 20));

  qk_calib<<<1, 64, 0, stream>>>(x, W_attn);
  for (int b0 = 0; b0 < 8; b0 += CB) {
    qk_gemm_f64<<<dim3(32, 16 * CB), 256, 0, stream>>>(x, W_attn, b_attn, qT, kT, b0);
    v_gemm_f32<<<dim3(8, 8 * CB), 256, 0, stream>>>(x, W_attn, b_attn, Vp, b0);
    attn_fused<<<dim3(16, 16 * CB), 256, 0, stream>>>(qT, kT, Vp, mask, AO, b0);
    proj_gemm<<<dim3(8, 8 * CB), 256, 0, stream>>>(AO, W_proj, b_proj, out, b0);
  }
}